// Round 6
// baseline (217.759 us; speedup 1.0000x reference)
//
#include <hip/hip_runtime.h>
#include <hip/hip_bf16.h>
#include <math.h>

typedef __bf16 bf16_t;
typedef __attribute__((ext_vector_type(8))) __bf16 bf16x8;
typedef __attribute__((ext_vector_type(4))) __bf16 bf16x4;
typedef __attribute__((ext_vector_type(4))) float f32x4;

#define MFMA_16x16x32(A_, B_, C_) __builtin_amdgcn_mfma_f32_16x16x32_bf16((A_), (B_), (C_), 0, 0, 0)

#define Bsz 4
#define Ssz 2048
#define Dsz 1024
#define Hh 16
#define DKd 64
#define Mrows (Bsz * Ssz)  /* 8192 */
#define N1 (3 * Dsz)       /* 3072 */
#define KD Dsz             /* 1024 */

// ---------------- f32 -> bf16 conversion (x4 vectorized) ----------------
__global__ void cvt_f32_bf16_kernel(const float* __restrict__ src, bf16_t* __restrict__ dst, int n4) {
  int i = blockIdx.x * blockDim.x + threadIdx.x;
  if (i >= n4) return;
  float4 v = reinterpret_cast<const float4*>(src)[i];
  bf16x4 o = {(bf16_t)v.x, (bf16_t)v.y, (bf16_t)v.z, (bf16_t)v.w};
  reinterpret_cast<bf16x4*>(dst)[i] = o;
}

// ---------------- RoPE cos/sin table: [S][32] float2 ----------------
__global__ void rope_tab_kernel(const int* __restrict__ pos, float2* __restrict__ tab) {
  int i = blockIdx.x * blockDim.x + threadIdx.x;
  if (i >= Ssz * 32) return;
  int s = i >> 5, f = i & 31;
  float inv_freq = powf(10000.0f, -(float)(2 * f) / 64.0f);
  float a = (float)pos[s] * inv_freq;
  tab[i] = make_float2(cosf(a), sinf(a));
}

// ---------------- TN GEMM: C[M][N] = A[M][K] * Bt[N][K]^T ----------------
// 128x128 tile, BK=32, 4 waves (2x2). 2-phase double-buffered K-loop:
// STAGE(next tile via global_load_lds w=16) -> ds_read+MFMA(cur) -> 1 barrier.
// Load latency hides under current tile's compute (T3 minimum recipe).
// Source-side chunk XOR-swizzle (chunk ^= (row>>1)&3) + matching ds_read
// swizzle -> conflict-free (verified 0 in R5).
template <int EPI>
__global__ __launch_bounds__(256, 3) void gemm_tn_kernel(
    const bf16_t* __restrict__ A, const bf16_t* __restrict__ Bt, int Kdim, int ldcN,
    bf16_t* __restrict__ qb, bf16_t* __restrict__ kb, bf16_t* __restrict__ vtb,
    const float2* __restrict__ tab, float* __restrict__ fout) {
  __shared__ __align__(16) bf16_t As[2][128 * 32];
  __shared__ __align__(16) bf16_t Bs[2][128 * 32];
  const int t = threadIdx.x;
  const int w = t >> 6, l = t & 63;
  const int lr = l & 15, lk = l >> 4;
  const int wm = w >> 1, wn = w & 1;
  const int m0 = blockIdx.y * 128, n0 = blockIdx.x * 128;

  // staging: lane's LDS chunk = t&3 holds global chunk (t&3)^((row>>1)&3)
  const int srow = t >> 2;
  const int schunk = (t & 3) ^ ((t >> 3) & 3);
  const bf16_t* gA = A + (size_t)(m0 + srow) * Kdim + schunk * 8;
  const bf16_t* gB = Bt + (size_t)(n0 + srow) * Kdim + schunk * 8;

  f32x4 acc[4][4] = {};
  const int rsw = (lr >> 1) & 3;  // read-side swizzle

#define STAGE_(PH, KT)                                                                   \
  do {                                                                                   \
    __builtin_amdgcn_global_load_lds(gA + (KT), &As[PH][(w * 16) * 32], 16, 0, 0);       \
    __builtin_amdgcn_global_load_lds(gA + (size_t)64 * Kdim + (KT),                      \
                                     &As[PH][(64 + w * 16) * 32], 16, 0, 0);             \
    __builtin_amdgcn_global_load_lds(gB + (KT), &Bs[PH][(w * 16) * 32], 16, 0, 0);       \
    __builtin_amdgcn_global_load_lds(gB + (size_t)64 * Kdim + (KT),                      \
                                     &Bs[PH][(64 + w * 16) * 32], 16, 0, 0);             \
  } while (0)

#define COMPUTE_(PH)                                                                     \
  do {                                                                                   \
    bf16x8 af[4], bfv[4];                                                                \
    _Pragma("unroll") for (int m = 0; m < 4; ++m) af[m] =                                \
        *reinterpret_cast<const bf16x8*>(&As[PH][(wm * 64 + m * 16 + lr) * 32] +         \
                                         ((lk ^ rsw) * 8));                              \
    _Pragma("unroll") for (int n = 0; n < 4; ++n) bfv[n] =                               \
        *reinterpret_cast<const bf16x8*>(&Bs[PH][(wn * 64 + n * 16 + lr) * 32] +         \
                                         ((lk ^ rsw) * 8));                              \
    _Pragma("unroll") for (int m = 0; m < 4; ++m) _Pragma("unroll") for (int n = 0;      \
                                                                         n < 4; ++n)    \
        acc[m][n] = MFMA_16x16x32(af[m], bfv[n], acc[m][n]);                             \
  } while (0)

  STAGE_(0, 0);
  __syncthreads();  // prologue: buf0 ready (barrier drains vmcnt)
  for (int kt = 0; kt < Kdim; kt += 64) {
    STAGE_(1, kt + 32);          // prefetch hides under compute below
    COMPUTE_(0);
    __syncthreads();             // buf1 staged + buf0 consumed
    if (kt + 64 < Kdim) STAGE_(0, kt + 64);
    COMPUTE_(1);
    __syncthreads();
  }
#undef STAGE_
#undef COMPUTE_

  if (EPI == 0) {
#pragma unroll
    for (int n = 0; n < 4; ++n) {
      const int col = n0 + wn * 64 + n * 16 + lr;
      const int sect = col >> 10;
      const int h = (col >> 6) & 15;
      const int dk = col & 63;
#pragma unroll
      for (int m = 0; m < 4; ++m) {
        const int growb = m0 + wm * 64 + m * 16 + lk * 4;
#pragma unroll
        for (int r = 0; r < 4; ++r) {
          const int grow = growb + r;
          const int bb = grow >> 11;
          const int s = grow & (Ssz - 1);
          float v = acc[m][n][r];
          if (sect < 2) {
            const float pv = __shfl_xor(v, 1);
            const float2 cs = tab[(s << 5) | (dk >> 1)];
            float vr = (dk & 1) ? (pv * cs.y + v * cs.x) : (v * cs.x - pv * cs.y);
            const size_t idx = ((size_t)((bb * Hh + h) * Ssz + s)) * DKd + dk;
            if (sect == 0)
              qb[idx] = (bf16_t)(vr * 0.125f);
            else
              kb[idx] = (bf16_t)vr;
          } else {
            vtb[((size_t)(bb * Hh + h) * DKd + dk) * Ssz + s] = (bf16_t)v;
          }
        }
      }
    }
  } else {
#pragma unroll
    for (int m = 0; m < 4; ++m)
#pragma unroll
      for (int r = 0; r < 4; ++r) {
        const int grow = m0 + wm * 64 + m * 16 + lk * 4 + r;
        float* op = fout + (size_t)grow * ldcN + n0 + wn * 64 + lr;
#pragma unroll
        for (int n = 0; n < 4; ++n) op[n * 16] = acc[m][n][r];
      }
  }
}

// ---------------- causal flash attention, swapped-QK^T / in-lane softmax ----
__global__ __launch_bounds__(256, 3) void attn_kernel(
    const bf16_t* __restrict__ qb, const bf16_t* __restrict__ kb,
    const bf16_t* __restrict__ vtb, bf16_t* __restrict__ aout) {
  __shared__ __align__(16) bf16_t Ks[64 * 64];
  __shared__ __align__(16) bf16_t Vs[64 * 64];
  const int t = threadIdx.x, w = t >> 6, l = t & 63;
  const int lr = l & 15, lk = l >> 4;
  const int bid = blockIdx.x;
  const int bh = (bid & 7) * 8 + ((bid >> 3) & 7);
  const int qt = 15 - (bid >> 6);  // heavy-first
  const int q0 = qt * 128;
  const int sub0 = q0 + w * 32;

  const bf16_t* qbase = qb + ((size_t)bh * Ssz + sub0) * DKd;
  bf16x8 qf[2][2];
#pragma unroll
  for (int s = 0; s < 2; ++s) {
    qf[s][0] = *reinterpret_cast<const bf16x8*>(qbase + (s * 16 + lr) * DKd + lk * 8);
    qf[s][1] = *reinterpret_cast<const bf16x8*>(qbase + (s * 16 + lr) * DKd + 32 + lk * 8);
  }

  f32x4 o[2][4] = {};
  float mrow[2] = {-INFINITY, -INFINITY};
  float lsum[2] = {0.f, 0.f};

  const int srow = t >> 2;
  const int scc = (t & 3) * 2;
  const bf16_t* kg = kb + ((size_t)bh * Ssz + srow) * DKd + scc * 8;
  const bf16_t* vg = vtb + ((size_t)bh * DKd + srow) * Ssz + scc * 8;
  bf16_t* ksw0 = Ks + srow * 64 + ((scc ^ (srow & 7)) * 8);
  bf16_t* ksw1 = Ks + srow * 64 + (((scc + 1) ^ (srow & 7)) * 8);
  bf16_t* vw[4];
#pragma unroll
  for (int u = 0; u < 2; ++u) {
    const int c = scc + u;
    const int B = 32 * (c >> 2) + 16 * (c & 1) + 4 * ((c & 3) >> 1);
    const int ch = B >> 3, off = B & 7;
    vw[2 * u] = Vs + srow * 64 + ((ch ^ (srow & 7)) * 8) + off;
    vw[2 * u + 1] = Vs + srow * 64 + (((ch + 1) ^ (srow & 7)) * 8) + off;
  }

  const int kvend = q0 + 128;
  bf16x8 pk0 = *reinterpret_cast<const bf16x8*>(kg);
  bf16x8 pk1 = *reinterpret_cast<const bf16x8*>(kg + 8);
  bf16x8 pv0 = *reinterpret_cast<const bf16x8*>(vg);
  bf16x8 pv1 = *reinterpret_cast<const bf16x8*>(vg + 8);

  for (int kv = 0; kv < kvend; kv += 64) {
    __syncthreads();
    *reinterpret_cast<bf16x8*>(ksw0) = pk0;
    *reinterpret_cast<bf16x8*>(ksw1) = pk1;
    *reinterpret_cast<bf16x4*>(vw[0]) = __builtin_shufflevector(pv0, pv0, 0, 1, 2, 3);
    *reinterpret_cast<bf16x4*>(vw[1]) = __builtin_shufflevector(pv0, pv0, 4, 5, 6, 7);
    *reinterpret_cast<bf16x4*>(vw[2]) = __builtin_shufflevector(pv1, pv1, 0, 1, 2, 3);
    *reinterpret_cast<bf16x4*>(vw[3]) = __builtin_shufflevector(pv1, pv1, 4, 5, 6, 7);
    __syncthreads();
    if (kv + 64 < kvend) {
      pk0 = *reinterpret_cast<const bf16x8*>(kg + (size_t)(kv + 64) * DKd);
      pk1 = *reinterpret_cast<const bf16x8*>(kg + (size_t)(kv + 64) * DKd + 8);
      pv0 = *reinterpret_cast<const bf16x8*>(vg + kv + 64);
      pv1 = *reinterpret_cast<const bf16x8*>(vg + kv + 64 + 8);
    }
#pragma unroll
    for (int s = 0; s < 2; ++s) {
      const int subrow = sub0 + s * 16;
      if (kv > subrow + 15) continue;
      f32x4 sa[4];
#pragma unroll
      for (int n = 0; n < 4; ++n) {
        const int R = n * 16 + lr;
        const bf16x8 a0 = *reinterpret_cast<const bf16x8*>(Ks + R * 64 + ((lk ^ (R & 7)) * 8));
        const bf16x8 a1 = *reinterpret_cast<const bf16x8*>(Ks + R * 64 + (((lk + 4) ^ (R & 7)) * 8));
        f32x4 z = {};
        z = MFMA_16x16x32(a0, qf[s][0], z);
        z = MFMA_16x16x32(a1, qf[s][1], z);
        sa[n] = z;
      }
      if (kv + 63 > subrow) {
        const int qrow = subrow + lr;
        const int kbase = kv + lk * 4;
#pragma unroll
        for (int n = 0; n < 4; ++n)
#pragma unroll
          for (int r = 0; r < 4; ++r)
            if (kbase + n * 16 + r > qrow) sa[n][r] = -INFINITY;
      }
      float mx = fmaxf(fmaxf(fmaxf(sa[0][0], sa[0][1]), fmaxf(sa[0][2], sa[0][3])),
                       fmaxf(fmaxf(sa[1][0], sa[1][1]), fmaxf(sa[1][2], sa[1][3])));
      mx = fmaxf(mx, fmaxf(fmaxf(fmaxf(sa[2][0], sa[2][1]), fmaxf(sa[2][2], sa[2][3])),
                           fmaxf(fmaxf(sa[3][0], sa[3][1]), fmaxf(sa[3][2], sa[3][3]))));
      mx = fmaxf(mx, __shfl_xor(mx, 16));
      mx = fmaxf(mx, __shfl_xor(mx, 32));
      const float mnew = fmaxf(mrow[s], mx);
      const float scl = __expf(mrow[s] - mnew);
      mrow[s] = mnew;
      float ps = 0.f;
#pragma unroll
      for (int n = 0; n < 4; ++n)
#pragma unroll
        for (int r = 0; r < 4; ++r) {
          const float p = __expf(sa[n][r] - mnew);
          sa[n][r] = p;
          ps += p;
        }
      lsum[s] = lsum[s] * scl + ps;
#pragma unroll
      for (int n = 0; n < 4; ++n)
#pragma unroll
        for (int r = 0; r < 4; ++r) o[s][n][r] *= scl;
      bf16x8 pb0, pb1;
#pragma unroll
      for (int r = 0; r < 4; ++r) {
        pb0[r] = (bf16_t)sa[0][r];
        pb0[4 + r] = (bf16_t)sa[1][r];
        pb1[r] = (bf16_t)sa[2][r];
        pb1[4 + r] = (bf16_t)sa[3][r];
      }
#pragma unroll
      for (int n = 0; n < 4; ++n) {
        const int R = n * 16 + lr;
        const bf16x8 v0 = *reinterpret_cast<const bf16x8*>(Vs + R * 64 + ((lk ^ (R & 7)) * 8));
        const bf16x8 v1 = *reinterpret_cast<const bf16x8*>(Vs + R * 64 + (((lk + 4) ^ (R & 7)) * 8));
        o[s][n] = MFMA_16x16x32(v0, pb0, o[s][n]);
        o[s][n] = MFMA_16x16x32(v1, pb1, o[s][n]);
      }
    }
  }
  const int b_ = bh >> 4, h_ = bh & 15;
#pragma unroll
  for (int s = 0; s < 2; ++s) {
    float sm = lsum[s];
    sm += __shfl_xor(sm, 16);
    sm += __shfl_xor(sm, 32);
    const float inv = 1.0f / sm;
    const int qrow = sub0 + s * 16 + lr;
    bf16_t* op = aout + ((size_t)b_ * Ssz + qrow) * Dsz + h_ * DKd + lk * 4;
#pragma unroll
    for (int n = 0; n < 4; ++n) {
      const bf16x4 ov = {(bf16_t)(o[s][n][0] * inv), (bf16_t)(o[s][n][1] * inv),
                         (bf16_t)(o[s][n][2] * inv), (bf16_t)(o[s][n][3] * inv)};
      *reinterpret_cast<bf16x4*>(op + n * 16) = ov;
    }
  }
}

extern "C" void kernel_launch(void* const* d_in, const int* in_sizes, int n_in,
                              void* d_out, int out_size, void* d_ws, size_t ws_size,
                              hipStream_t stream) {
  const float* x = (const float*)d_in[0];
  const int* pos = (const int*)d_in[1];
  const float* wqkv = (const float*)d_in[2];
  const float* wo = (const float*)d_in[3];
  float* out = (float*)d_out;

  bf16_t* xb = (bf16_t*)d_ws;
  bf16_t* wqkvb = xb + (size_t)Mrows * KD;
  bf16_t* wob = wqkvb + (size_t)N1 * KD;
  bf16_t* qbuf = wob + (size_t)Dsz * KD;
  bf16_t* kbuf = qbuf + (size_t)64 * Ssz * DKd;
  bf16_t* vtb = kbuf + (size_t)64 * Ssz * DKd;
  float2* tab = (float2*)(vtb + (size_t)64 * Ssz * DKd);
  bf16_t* aout = xb;

  {
    int n4 = Mrows * KD / 4;
    cvt_f32_bf16_kernel<<<(n4 + 255) / 256, 256, 0, stream>>>(x, xb, n4);
  }
  {
    int n4 = N1 * KD / 4;
    cvt_f32_bf16_kernel<<<(n4 + 255) / 256, 256, 0, stream>>>(wqkv, wqkvb, n4);
  }
  {
    int n4 = Dsz * KD / 4;
    cvt_f32_bf16_kernel<<<(n4 + 255) / 256, 256, 0, stream>>>(wo, wob, n4);
  }
  rope_tab_kernel<<<(Ssz * 32 + 255) / 256, 256, 0, stream>>>(pos, tab);

  gemm_tn_kernel<0><<<dim3(N1 / 128, Mrows / 128), 256, 0, stream>>>(
      xb, wqkvb, KD, 0, qbuf, kbuf, vtb, tab, nullptr);

  attn_kernel<<<dim3(16 * 64), 256, 0, stream>>>(qbuf, kbuf, vtb, aout);

  gemm_tn_kernel<1><<<dim3(Dsz / 128, Mrows / 128), 256, 0, stream>>>(
      aout, wob, KD, Dsz, nullptr, nullptr, nullptr, nullptr, out);
}

// Round 7
// 197.890 us; speedup vs baseline: 1.1004x; 1.1004x over previous
//
#include <hip/hip_runtime.h>
#include <hip/hip_bf16.h>
#include <math.h>

typedef __bf16 bf16_t;
typedef __attribute__((ext_vector_type(8))) __bf16 bf16x8;
typedef __attribute__((ext_vector_type(4))) __bf16 bf16x4;
typedef __attribute__((ext_vector_type(4))) float f32x4;

#define MFMA_16x16x32(A_, B_, C_) __builtin_amdgcn_mfma_f32_16x16x32_bf16((A_), (B_), (C_), 0, 0, 0)

#define Bsz 4
#define Ssz 2048
#define Dsz 1024
#define Hh 16
#define DKd 64
#define Mrows (Bsz * Ssz)  /* 8192 */
#define N1 (3 * Dsz)       /* 3072 */
#define KD Dsz             /* 1024 */

// ---------------- f32 -> bf16 conversion (x4 vectorized) ----------------
__global__ void cvt_f32_bf16_kernel(const float* __restrict__ src, bf16_t* __restrict__ dst, int n4) {
  int i = blockIdx.x * blockDim.x + threadIdx.x;
  if (i >= n4) return;
  float4 v = reinterpret_cast<const float4*>(src)[i];
  bf16x4 o = {(bf16_t)v.x, (bf16_t)v.y, (bf16_t)v.z, (bf16_t)v.w};
  reinterpret_cast<bf16x4*>(dst)[i] = o;
}

// ---------------- RoPE cos/sin table: [S][32] float2 ----------------
__global__ void rope_tab_kernel(const int* __restrict__ pos, float2* __restrict__ tab) {
  int i = blockIdx.x * blockDim.x + threadIdx.x;
  if (i >= Ssz * 32) return;
  int s = i >> 5, f = i & 31;
  float inv_freq = powf(10000.0f, -(float)(2 * f) / 64.0f);
  float a = (float)pos[s] * inv_freq;
  tab[i] = make_float2(cosf(a), sinf(a));
}

// ============ QKV GEMM: 256x256 tile, BK=64, 8 waves (2Mx4N) ============
// 64 MFMA/wave per K-tile between barriers (4x the 128x128 structure).
// Double-buffered 128 KiB LDS; global_load_lds w=16, all 8 issues at tile
// top so the swap drain hides under ~2000 cyc of MFMA. Source-side chunk
// XOR swizzle (chunk ^= (row>>1)&7), read side ^ (lr>>1): 2-way = free.
__global__ __launch_bounds__(512, 2) void gemm256_qkv_kernel(
    const bf16_t* __restrict__ A, const bf16_t* __restrict__ Bt,
    bf16_t* __restrict__ qb, bf16_t* __restrict__ kb, bf16_t* __restrict__ vtb,
    const float2* __restrict__ tab) {
  __shared__ __align__(16) bf16_t As[2][256 * 64];
  __shared__ __align__(16) bf16_t Bs[2][256 * 64];
  const int t = threadIdx.x;
  const int w = t >> 6, l = t & 63;
  const int lr = l & 15, lk = l >> 4;
  const int rs = lr >> 1;            // read-side swizzle
  const int wm = w >> 2, wn = w & 3; // 2M x 4N waves
  const int m0 = blockIdx.y * 256, n0 = blockIdx.x * 256;

  // staging: issue i covers rows i*64..i*64+63; thread t -> row trow, chunk
  // (t&7), whose DATA is global chunk (t&7)^((row>>1)&7) = (t&7)^((t>>4)&7)
  const int trow = t >> 3;
  const int schunk = (t & 7) ^ ((t >> 4) & 7);
  const bf16_t* gAs[4];
  const bf16_t* gBs[4];
#pragma unroll
  for (int i = 0; i < 4; ++i) {
    gAs[i] = A + (size_t)(m0 + i * 64 + trow) * KD + schunk * 8;
    gBs[i] = Bt + (size_t)(n0 + i * 64 + trow) * KD + schunk * 8;
  }

  f32x4 acc[8][4] = {};

  // prologue: stage tile 0 into buf 0
#pragma unroll
  for (int i = 0; i < 4; ++i) {
    __builtin_amdgcn_global_load_lds(gAs[i], &As[0][(i * 64 + w * 8) * 64], 16, 0, 0);
    __builtin_amdgcn_global_load_lds(gBs[i], &Bs[0][(i * 64 + w * 8) * 64], 16, 0, 0);
  }
  __syncthreads();

  for (int tt = 0; tt < KD / 64; ++tt) {
    const int b = tt & 1;
    if (tt + 1 < KD / 64) {
      const int kt = (tt + 1) * 64;
#pragma unroll
      for (int i = 0; i < 4; ++i) {
        __builtin_amdgcn_global_load_lds(gAs[i] + kt, &As[b ^ 1][(i * 64 + w * 8) * 64], 16, 0, 0);
        __builtin_amdgcn_global_load_lds(gBs[i] + kt, &Bs[b ^ 1][(i * 64 + w * 8) * 64], 16, 0, 0);
      }
    }
    // B fragments for this K-tile (kept across the 4 phases)
    bf16x8 bfv[4][2];
#pragma unroll
    for (int n = 0; n < 4; ++n) {
      const int R = wn * 64 + n * 16 + lr;
#pragma unroll
      for (int ks = 0; ks < 2; ++ks)
        bfv[n][ks] = *reinterpret_cast<const bf16x8*>(&Bs[b][R * 64 + (((ks * 4 + lk) ^ rs) * 8)]);
    }
#pragma unroll
    for (int mp = 0; mp < 4; ++mp) {
      bf16x8 af[2][2];
#pragma unroll
      for (int mi = 0; mi < 2; ++mi) {
        const int R = wm * 128 + (mp * 2 + mi) * 16 + lr;
#pragma unroll
        for (int ks = 0; ks < 2; ++ks)
          af[mi][ks] = *reinterpret_cast<const bf16x8*>(&As[b][R * 64 + (((ks * 4 + lk) ^ rs) * 8)]);
      }
      __builtin_amdgcn_s_setprio(1);
#pragma unroll
      for (int mi = 0; mi < 2; ++mi)
#pragma unroll
        for (int n = 0; n < 4; ++n) {
          acc[mp * 2 + mi][n] = MFMA_16x16x32(af[mi][0], bfv[n][0], acc[mp * 2 + mi][n]);
          acc[mp * 2 + mi][n] = MFMA_16x16x32(af[mi][1], bfv[n][1], acc[mp * 2 + mi][n]);
        }
      __builtin_amdgcn_s_setprio(0);
    }
    __syncthreads();  // drains this wave's stage loads; buf[b] consumed
  }

  // ---- epilogue: RoPE for q/k, transposed scatter for v ----
  const int sect = n0 >> 10;                  // uniform per block
  const int hh = ((n0 + wn * 64) >> 6) & 15;  // uniform per wave
  if (sect < 2) {
#pragma unroll
    for (int m = 0; m < 8; ++m)
#pragma unroll
      for (int r = 0; r < 4; ++r) {
        const int grow = m0 + wm * 128 + m * 16 + lk * 4 + r;
        const int bb = grow >> 11, s = grow & (Ssz - 1);
        const float2* tr = tab + (s << 5);
        bf16_t* basep = (sect == 0 ? qb : kb) + ((size_t)(bb * Hh + hh) * Ssz + s) * DKd;
#pragma unroll
        for (int n = 0; n < 4; ++n) {
          const float v = acc[m][n][r];
          const float pv = __shfl_xor(v, 1);
          const int dk = n * 16 + lr;
          const float2 cs = tr[dk >> 1];
          float vr = (dk & 1) ? (pv * cs.y + v * cs.x) : (v * cs.x - pv * cs.y);
          if (sect == 0) vr *= 0.125f;
          basep[dk] = (bf16_t)vr;
        }
      }
  } else {
#pragma unroll
    for (int m = 0; m < 8; ++m)
#pragma unroll
      for (int r = 0; r < 4; ++r) {
        const int grow = m0 + wm * 128 + m * 16 + lk * 4 + r;
        const int bb = grow >> 11, s = grow & (Ssz - 1);
        bf16_t* vb = vtb + (size_t)(bb * Hh + hh) * DKd * Ssz + s;
#pragma unroll
        for (int n = 0; n < 4; ++n)
          vb[(size_t)(n * 16 + lr) * Ssz] = (bf16_t)acc[m][n][r];
      }
  }
}

// ---------------- out-proj GEMM: 128x128 m97 structure (unchanged) -------
__global__ __launch_bounds__(256, 3) void gemm_out_kernel(
    const bf16_t* __restrict__ A, const bf16_t* __restrict__ Bt, int Kdim, int ldcN,
    float* __restrict__ fout) {
  __shared__ __align__(16) bf16_t As[2][128 * 32];
  __shared__ __align__(16) bf16_t Bs[2][128 * 32];
  const int t = threadIdx.x;
  const int w = t >> 6, l = t & 63;
  const int lr = l & 15, lk = l >> 4;
  const int wm = w >> 1, wn = w & 1;
  const int m0 = blockIdx.y * 128, n0 = blockIdx.x * 128;

  const int srow = t >> 2;
  const int schunk = (t & 3) ^ ((t >> 3) & 3);
  const bf16_t* gA = A + (size_t)(m0 + srow) * Kdim + schunk * 8;
  const bf16_t* gB = Bt + (size_t)(n0 + srow) * Kdim + schunk * 8;

  f32x4 acc[4][4] = {};
  const int rsw = (lr >> 1) & 3;

#define STAGE_(PH, KT)                                                                   \
  do {                                                                                   \
    __builtin_amdgcn_global_load_lds(gA + (KT), &As[PH][(w * 16) * 32], 16, 0, 0);       \
    __builtin_amdgcn_global_load_lds(gA + (size_t)64 * Kdim + (KT),                      \
                                     &As[PH][(64 + w * 16) * 32], 16, 0, 0);             \
    __builtin_amdgcn_global_load_lds(gB + (KT), &Bs[PH][(w * 16) * 32], 16, 0, 0);       \
    __builtin_amdgcn_global_load_lds(gB + (size_t)64 * Kdim + (KT),                      \
                                     &Bs[PH][(64 + w * 16) * 32], 16, 0, 0);             \
  } while (0)

#define COMPUTE_(PH)                                                                     \
  do {                                                                                   \
    bf16x8 af[4], bfv[4];                                                                \
    _Pragma("unroll") for (int m = 0; m < 4; ++m) af[m] =                                \
        *reinterpret_cast<const bf16x8*>(&As[PH][(wm * 64 + m * 16 + lr) * 32] +         \
                                         ((lk ^ rsw) * 8));                              \
    _Pragma("unroll") for (int n = 0; n < 4; ++n) bfv[n] =                               \
        *reinterpret_cast<const bf16x8*>(&Bs[PH][(wn * 64 + n * 16 + lr) * 32] +         \
                                         ((lk ^ rsw) * 8));                              \
    _Pragma("unroll") for (int m = 0; m < 4; ++m) _Pragma("unroll") for (int n = 0;      \
                                                                         n < 4; ++n)    \
        acc[m][n] = MFMA_16x16x32(af[m], bfv[n], acc[m][n]);                             \
  } while (0)

  STAGE_(0, 0);
  __syncthreads();
  for (int kt = 0; kt < Kdim; kt += 64) {
    STAGE_(1, kt + 32);
    COMPUTE_(0);
    __syncthreads();
    if (kt + 64 < Kdim) STAGE_(0, kt + 64);
    COMPUTE_(1);
    __syncthreads();
  }
#undef STAGE_
#undef COMPUTE_

#pragma unroll
  for (int m = 0; m < 4; ++m)
#pragma unroll
    for (int r = 0; r < 4; ++r) {
      const int grow = m0 + wm * 64 + m * 16 + lk * 4 + r;
      float* op = fout + (size_t)grow * ldcN + n0 + wn * 64 + lr;
#pragma unroll
      for (int n = 0; n < 4; ++n) op[n * 16] = acc[m][n][r];
    }
}

// ---------------- causal flash attention, swapped-QK^T / in-lane softmax ----
__global__ __launch_bounds__(256, 3) void attn_kernel(
    const bf16_t* __restrict__ qb, const bf16_t* __restrict__ kb,
    const bf16_t* __restrict__ vtb, bf16_t* __restrict__ aout) {
  __shared__ __align__(16) bf16_t Ks[64 * 64];
  __shared__ __align__(16) bf16_t Vs[64 * 64];
  const int t = threadIdx.x, w = t >> 6, l = t & 63;
  const int lr = l & 15, lk = l >> 4;
  const int bid = blockIdx.x;
  const int bh = (bid & 7) * 8 + ((bid >> 3) & 7);
  const int qt = 15 - (bid >> 6);  // heavy-first
  const int q0 = qt * 128;
  const int sub0 = q0 + w * 32;

  const bf16_t* qbase = qb + ((size_t)bh * Ssz + sub0) * DKd;
  bf16x8 qf[2][2];
#pragma unroll
  for (int s = 0; s < 2; ++s) {
    qf[s][0] = *reinterpret_cast<const bf16x8*>(qbase + (s * 16 + lr) * DKd + lk * 8);
    qf[s][1] = *reinterpret_cast<const bf16x8*>(qbase + (s * 16 + lr) * DKd + 32 + lk * 8);
  }

  f32x4 o[2][4] = {};
  float mrow[2] = {-INFINITY, -INFINITY};
  float lsum[2] = {0.f, 0.f};

  const int srow = t >> 2;
  const int scc = (t & 3) * 2;
  const bf16_t* kg = kb + ((size_t)bh * Ssz + srow) * DKd + scc * 8;
  const bf16_t* vg = vtb + ((size_t)bh * DKd + srow) * Ssz + scc * 8;
  bf16_t* ksw0 = Ks + srow * 64 + ((scc ^ (srow & 7)) * 8);
  bf16_t* ksw1 = Ks + srow * 64 + (((scc + 1) ^ (srow & 7)) * 8);
  bf16_t* vw[4];
#pragma unroll
  for (int u = 0; u < 2; ++u) {
    const int c = scc + u;
    const int B = 32 * (c >> 2) + 16 * (c & 1) + 4 * ((c & 3) >> 1);
    const int ch = B >> 3, off = B & 7;
    vw[2 * u] = Vs + srow * 64 + ((ch ^ (srow & 7)) * 8) + off;
    vw[2 * u + 1] = Vs + srow * 64 + (((ch + 1) ^ (srow & 7)) * 8) + off;
  }

  const int kvend = q0 + 128;
  bf16x8 pk0 = *reinterpret_cast<const bf16x8*>(kg);
  bf16x8 pk1 = *reinterpret_cast<const bf16x8*>(kg + 8);
  bf16x8 pv0 = *reinterpret_cast<const bf16x8*>(vg);
  bf16x8 pv1 = *reinterpret_cast<const bf16x8*>(vg + 8);

  for (int kv = 0; kv < kvend; kv += 64) {
    __syncthreads();
    *reinterpret_cast<bf16x8*>(ksw0) = pk0;
    *reinterpret_cast<bf16x8*>(ksw1) = pk1;
    *reinterpret_cast<bf16x4*>(vw[0]) = __builtin_shufflevector(pv0, pv0, 0, 1, 2, 3);
    *reinterpret_cast<bf16x4*>(vw[1]) = __builtin_shufflevector(pv0, pv0, 4, 5, 6, 7);
    *reinterpret_cast<bf16x4*>(vw[2]) = __builtin_shufflevector(pv1, pv1, 0, 1, 2, 3);
    *reinterpret_cast<bf16x4*>(vw[3]) = __builtin_shufflevector(pv1, pv1, 4, 5, 6, 7);
    __syncthreads();
    if (kv + 64 < kvend) {
      pk0 = *reinterpret_cast<const bf16x8*>(kg + (size_t)(kv + 64) * DKd);
      pk1 = *reinterpret_cast<const bf16x8*>(kg + (size_t)(kv + 64) * DKd + 8);
      pv0 = *reinterpret_cast<const bf16x8*>(vg + kv + 64);
      pv1 = *reinterpret_cast<const bf16x8*>(vg + kv + 64 + 8);
    }
#pragma unroll
    for (int s = 0; s < 2; ++s) {
      const int subrow = sub0 + s * 16;
      if (kv > subrow + 15) continue;
      f32x4 sa[4];
#pragma unroll
      for (int n = 0; n < 4; ++n) {
        const int R = n * 16 + lr;
        const bf16x8 a0 = *reinterpret_cast<const bf16x8*>(Ks + R * 64 + ((lk ^ (R & 7)) * 8));
        const bf16x8 a1 = *reinterpret_cast<const bf16x8*>(Ks + R * 64 + (((lk + 4) ^ (R & 7)) * 8));
        f32x4 z = {};
        z = MFMA_16x16x32(a0, qf[s][0], z);
        z = MFMA_16x16x32(a1, qf[s][1], z);
        sa[n] = z;
      }
      if (kv + 63 > subrow) {
        const int qrow = subrow + lr;
        const int kbase = kv + lk * 4;
#pragma unroll
        for (int n = 0; n < 4; ++n)
#pragma unroll
          for (int r = 0; r < 4; ++r)
            if (kbase + n * 16 + r > qrow) sa[n][r] = -INFINITY;
      }
      float mx = fmaxf(fmaxf(fmaxf(sa[0][0], sa[0][1]), fmaxf(sa[0][2], sa[0][3])),
                       fmaxf(fmaxf(sa[1][0], sa[1][1]), fmaxf(sa[1][2], sa[1][3])));
      mx = fmaxf(mx, fmaxf(fmaxf(fmaxf(sa[2][0], sa[2][1]), fmaxf(sa[2][2], sa[2][3])),
                           fmaxf(fmaxf(sa[3][0], sa[3][1]), fmaxf(sa[3][2], sa[3][3]))));
      mx = fmaxf(mx, __shfl_xor(mx, 16));
      mx = fmaxf(mx, __shfl_xor(mx, 32));
      const float mnew = fmaxf(mrow[s], mx);
      const float scl = __expf(mrow[s] - mnew);
      mrow[s] = mnew;
      float ps = 0.f;
#pragma unroll
      for (int n = 0; n < 4; ++n)
#pragma unroll
        for (int r = 0; r < 4; ++r) {
          const float p = __expf(sa[n][r] - mnew);
          sa[n][r] = p;
          ps += p;
        }
      lsum[s] = lsum[s] * scl + ps;
#pragma unroll
      for (int n = 0; n < 4; ++n)
#pragma unroll
        for (int r = 0; r < 4; ++r) o[s][n][r] *= scl;
      bf16x8 pb0, pb1;
#pragma unroll
      for (int r = 0; r < 4; ++r) {
        pb0[r] = (bf16_t)sa[0][r];
        pb0[4 + r] = (bf16_t)sa[1][r];
        pb1[r] = (bf16_t)sa[2][r];
        pb1[4 + r] = (bf16_t)sa[3][r];
      }
#pragma unroll
      for (int n = 0; n < 4; ++n) {
        const int R = n * 16 + lr;
        const bf16x8 v0 = *reinterpret_cast<const bf16x8*>(Vs + R * 64 + ((lk ^ (R & 7)) * 8));
        const bf16x8 v1 = *reinterpret_cast<const bf16x8*>(Vs + R * 64 + (((lk + 4) ^ (R & 7)) * 8));
        o[s][n] = MFMA_16x16x32(v0, pb0, o[s][n]);
        o[s][n] = MFMA_16x16x32(v1, pb1, o[s][n]);
      }
    }
  }
  const int b_ = bh >> 4, h_ = bh & 15;
#pragma unroll
  for (int s = 0; s < 2; ++s) {
    float sm = lsum[s];
    sm += __shfl_xor(sm, 16);
    sm += __shfl_xor(sm, 32);
    const float inv = 1.0f / sm;
    const int qrow = sub0 + s * 16 + lr;
    bf16_t* op = aout + ((size_t)b_ * Ssz + qrow) * Dsz + h_ * DKd + lk * 4;
#pragma unroll
    for (int n = 0; n < 4; ++n) {
      const bf16x4 ov = {(bf16_t)(o[s][n][0] * inv), (bf16_t)(o[s][n][1] * inv),
                         (bf16_t)(o[s][n][2] * inv), (bf16_t)(o[s][n][3] * inv)};
      *reinterpret_cast<bf16x4*>(op + n * 16) = ov;
    }
  }
}

extern "C" void kernel_launch(void* const* d_in, const int* in_sizes, int n_in,
                              void* d_out, int out_size, void* d_ws, size_t ws_size,
                              hipStream_t stream) {
  const float* x = (const float*)d_in[0];
  const int* pos = (const int*)d_in[1];
  const float* wqkv = (const float*)d_in[2];
  const float* wo = (const float*)d_in[3];
  float* out = (float*)d_out;

  bf16_t* xb = (bf16_t*)d_ws;
  bf16_t* wqkvb = xb + (size_t)Mrows * KD;
  bf16_t* wob = wqkvb + (size_t)N1 * KD;
  bf16_t* qbuf = wob + (size_t)Dsz * KD;
  bf16_t* kbuf = qbuf + (size_t)64 * Ssz * DKd;
  bf16_t* vtb = kbuf + (size_t)64 * Ssz * DKd;
  float2* tab = (float2*)(vtb + (size_t)64 * Ssz * DKd);
  bf16_t* aout = xb;

  {
    int n4 = Mrows * KD / 4;
    cvt_f32_bf16_kernel<<<(n4 + 255) / 256, 256, 0, stream>>>(x, xb, n4);
  }
  {
    int n4 = N1 * KD / 4;
    cvt_f32_bf16_kernel<<<(n4 + 255) / 256, 256, 0, stream>>>(wqkv, wqkvb, n4);
  }
  {
    int n4 = Dsz * KD / 4;
    cvt_f32_bf16_kernel<<<(n4 + 255) / 256, 256, 0, stream>>>(wo, wob, n4);
  }
  rope_tab_kernel<<<(Ssz * 32 + 255) / 256, 256, 0, stream>>>(pos, tab);

  gemm256_qkv_kernel<<<dim3(N1 / 256, Mrows / 256), 512, 0, stream>>>(
      xb, wqkvb, qbuf, kbuf, vtb, tab);

  attn_kernel<<<dim3(16 * 64), 256, 0, stream>>>(qbuf, kbuf, vtb, aout);

  gemm_out_kernel<<<dim3(Dsz / 128, Mrows / 128), 256, 0, stream>>>(
      aout, wob, KD, Dsz, out);
}